// Round 18
// baseline (158.357 us; speedup 1.0000x reference)
//
#include <hip/hip_runtime.h>

typedef short bf8 __attribute__((ext_vector_type(8)));
typedef float f32x4 __attribute__((ext_vector_type(4)));

__device__ inline short f2bfs(float f) {
    unsigned u = __builtin_bit_cast(unsigned, f);
    u += 0x7FFFu + ((u >> 16) & 1u);
    return (short)(u >> 16);
}

__device__ inline unsigned pk2(float x, float y) {
    return (unsigned)(unsigned short)f2bfs(x) |
           ((unsigned)(unsigned short)f2bfs(y) << 16);
}

__device__ inline float bf2f(short s) {
    unsigned u = ((unsigned)(unsigned short)s) << 16;
    return __builtin_bit_cast(float, u);
}

__device__ inline bf8 cvt_frag(f32x4 lo, f32x4 hi) {
    union { bf8 v; unsigned u[4]; } r;
    r.u[0] = pk2(lo[0], lo[1]);
    r.u[1] = pk2(lo[2], lo[3]);
    r.u[2] = pk2(hi[0], hi[1]);
    r.u[3] = pk2(hi[2], hi[3]);
    return r.v;
}

__device__ inline float fast_tanh(float x) {
    x = fminf(fmaxf(x, -15.f), 15.f);
    float e = __expf(2.f * x);
    return (e - 1.f) / (e + 1.f);
}

__device__ inline void gl_lds16(const void* g, void* l) {
    __builtin_amdgcn_global_load_lds(
        (const __attribute__((address_space(1))) unsigned int*)g,
        (__attribute__((address_space(3))) unsigned int*)l,
        16, 0, 0);
}

#define BAR() asm volatile("s_barrier" ::: "memory")

template<int N> __device__ __forceinline__ void waitvm() {
    if constexpr (N == 12)     asm volatile("s_waitcnt vmcnt(12)" ::: "memory");
    else if constexpr (N == 8) asm volatile("s_waitcnt vmcnt(8)"  ::: "memory");
    else if constexpr (N == 6) asm volatile("s_waitcnt vmcnt(6)"  ::: "memory");
    else if constexpr (N == 4) asm volatile("s_waitcnt vmcnt(4)"  ::: "memory");
    else if constexpr (N == 3) asm volatile("s_waitcnt vmcnt(3)"  ::: "memory");
    else                       asm volatile("s_waitcnt vmcnt(0)"  ::: "memory");
}

#define MFMA16 __builtin_amdgcn_mfma_f32_16x16x32_bf16

// C[M,N] = A[M,K] @ W[N,K]^T (+bias, +epilogue). BN=64, BK=32, 4 waves (2x2).
// A bf16 (pitch lda), W fp32 (cvt to bf16 on LDS read).
// 3-buffer LDS pipeline, depth-2 prefetch, counted vmcnt + raw s_barrier.
// EPI 0: C = acc + bias        EPI 1: BN-inference (q0..q3 = gamma,beta,mean,var)
// EPI 2: atomicAdd(score[m], sum_n fast_tanh(acc+bias[n]+q0[(m>>6)*N+n])*q1[n])
template<int EPI, int BM_, bool OBF>
__device__ __forceinline__ void gemm_body(
    char* smem,
    const short* __restrict__ A, const float* __restrict__ W,
    const float* __restrict__ bias, void* __restrict__ Cv,
    int N, int K, int lda, int n0, int m0,
    const float* __restrict__ q0, const float* __restrict__ q1,
    const float* __restrict__ q2, const float* __restrict__ q3,
    float* __restrict__ score)
{
    constexpr int FM  = BM_ / 32;      // m-frags per wave
    constexpr int ATS = BM_ * 64;      // A tile bytes (BM_ x 32 bf16)
    constexpr int LPT = (BM_ == 128) ? 4 : 3;   // loads/tile/wave

    const int lane = threadIdx.x & 63;
    const int wave = threadIdx.x >> 6;
    const int wm0  = (wave >> 1) * (BM_ / 2);
    const int wn0  = (wave & 1) * 32;
    const int lr   = lane & 15;
    const int g    = lane >> 4;

    f32x4 acc[FM][2] = {};

    auto stage = [&](int buf, int k0) {
        char* sA = smem + buf * ATS;
        char* sW = smem + 3 * ATS + buf * 8192;
        #pragma unroll
        for (int cc = 0; cc < BM_ / 64; ++cc) {
            int c  = wave * (BM_ / 64) + cc;
            int r  = c * 16 + (lane >> 2);
            int ss = (lane & 3) ^ ((r >> 1) & 3);
            gl_lds16(&A[(size_t)(m0 + r) * lda + k0 + ss * 8], sA + c * 1024);
        }
        #pragma unroll
        for (int cc = 0; cc < 2; ++cc) {
            int c  = wave * 2 + cc;
            int r  = c * 8 + (lane >> 3);
            int ss = (lane & 7) ^ (r & 7);
            int rg = n0 + r; rg = rg < N ? rg : N - 1;   // clamp tail
            gl_lds16(&W[(size_t)rg * K + k0 + ss * 4], sW + c * 1024);
        }
    };

    auto compute = [&](int buf) {
        char* sA = smem + buf * ATS;
        char* sW = smem + 3 * ATS + buf * 8192;
        bf8 av[FM], bv[2];
        #pragma unroll
        for (int i = 0; i < FM; ++i) {
            int ra = wm0 + i * 16 + lr;
            int sl = g ^ ((ra >> 1) & 3);
            av[i] = *reinterpret_cast<const bf8*>(sA + ra * 64 + sl * 16);
        }
        #pragma unroll
        for (int j = 0; j < 2; ++j) {
            int rb = wn0 + j * 16 + lr;
            int l0 = (2 * g)     ^ (rb & 7);
            int l1 = (2 * g + 1) ^ (rb & 7);
            f32x4 lo = *reinterpret_cast<const f32x4*>(sW + rb * 128 + l0 * 16);
            f32x4 hi = *reinterpret_cast<const f32x4*>(sW + rb * 128 + l1 * 16);
            bv[j] = cvt_frag(lo, hi);
        }
        #pragma unroll
        for (int i = 0; i < FM; ++i)
            #pragma unroll
            for (int j = 0; j < 2; ++j)
                acc[i][j] = MFMA16(av[i], bv[j], acc[i][j], 0, 0, 0);
    };

    const int nt = K >> 5;
    stage(0, 0); stage(1, 32);
    int bs = 2, bc = 0;
    for (int t = 0; t < nt - 2; ++t) {
        stage(bs, (t + 2) << 5);
        bs = (bs == 2) ? 0 : bs + 1;
        waitvm<2 * LPT>(); BAR();
        compute(bc);
        bc = (bc == 2) ? 0 : bc + 1;
        BAR();
    }
    waitvm<1 * LPT>(); BAR(); compute(bc); bc = (bc == 2) ? 0 : bc + 1; BAR();
    waitvm<0>();       BAR(); compute(bc);

    if constexpr (EPI == 2) {
        #pragma unroll
        for (int i = 0; i < FM; ++i) {
            #pragma unroll
            for (int r = 0; r < 4; ++r) {
                int m = m0 + wm0 + i * 16 + g * 4 + r;
                int bidx = m >> 6;
                float s = 0.f;
                #pragma unroll
                for (int j = 0; j < 2; ++j) {
                    int n = n0 + wn0 + j * 16 + lr;
                    s += fast_tanh(acc[i][j][r] + bias[n] + q0[(size_t)bidx * N + n]) * q1[n];
                }
                #pragma unroll
                for (int off = 1; off < 16; off <<= 1)
                    s += __shfl_xor(s, off);
                if (lr == 0) atomicAdd(&score[m], s);
            }
        }
    } else {
        #pragma unroll
        for (int j = 0; j < 2; ++j) {
            int n = n0 + wn0 + j * 16 + lr;
            if (n >= N) continue;
            float bn_ = bias[n];
            float sc = 1.f, sh = 0.f;
            if constexpr (EPI == 1) {
                sc = q0[n] * rsqrtf(q3[n] + 1e-3f);
                sh = q1[n] - q2[n] * sc;
            }
            #pragma unroll
            for (int i = 0; i < FM; ++i) {
                #pragma unroll
                for (int r = 0; r < 4; ++r) {
                    int m = m0 + wm0 + i * 16 + g * 4 + r;
                    float v = acc[i][j][r] + bn_;
                    if constexpr (EPI == 1) v = v * sc + sh;
                    if constexpr (OBF) ((short*)Cv)[(size_t)m * N + n] = f2bfs(v);
                    else               ((float*)Cv)[(size_t)m * N + n] = v;
                }
            }
        }
    }
}

template<int EPI, int BM_, bool OBF>
__global__ __launch_bounds__(256) void gemm_k(
    const short* __restrict__ A, const float* __restrict__ W,
    const float* __restrict__ bias, void* __restrict__ Cv,
    int N, int K, int lda,
    const float* __restrict__ q0, const float* __restrict__ q1,
    const float* __restrict__ q2, const float* __restrict__ q3,
    float* __restrict__ score)
{
    __shared__ __align__(1024) char smem[3 * BM_ * 64 + 3 * 8192];
    gemm_body<EPI, BM_, OBF>(smem, A, W, bias, Cv, N, K, lda,
                             blockIdx.x * 64, blockIdx.y * BM_,
                             q0, q1, q2, q3, score);
}

// z=0: C0 = A0@W0^T+b0 ; z=1: C1 = A1@W1^T+b1  (BM=64)
__global__ __launch_bounds__(256) void gemm_dual(
    const short* __restrict__ A0, const float* __restrict__ W0,
    const float* __restrict__ b0, float* __restrict__ C0,
    const short* __restrict__ A1, const float* __restrict__ W1,
    const float* __restrict__ b1, float* __restrict__ C1,
    int N, int K, int lda)
{
    __shared__ __align__(1024) char smem[3 * 64 * 64 + 3 * 8192];
    if (blockIdx.z == 0)
        gemm_body<0, 64, false>(smem, A0, W0, b0, C0, N, K, lda,
                                blockIdx.x * 64, blockIdx.y * 64,
                                nullptr, nullptr, nullptr, nullptr, nullptr);
    else
        gemm_body<0, 64, false>(smem, A1, W1, b1, C1, N, K, lda,
                                blockIdx.x * 64, blockIdx.y * 64,
                                nullptr, nullptr, nullptr, nullptr, nullptr);
}

// fc2 (BK=64): logits = y_bf @ fc2_w^T + fc2_b. BM=64, BN=64, BK=64, 16 iters.
// W rows stream as 256B contiguous bursts (vs 128B at BK=32) — tests the
// DRAM-granularity hypothesis. 3-buffer depth-2 counted-vmcnt; LPT=6
// (A: 2 chunks/wave, W: 4 chunks/wave); waits 12/6/0. 72KB LDS -> 2 blk/CU.
// A LDS: 64x64 bf16, 8 chunks (8 rows x 128B), slot^(row&7) swizzle.
// W LDS: 64x64 fp32, 16 chunks (4 rows x 256B), slot^(row&15) swizzle.
__global__ __launch_bounds__(256) void gemm_fc2(
    const short* __restrict__ A, const float* __restrict__ W,
    const float* __restrict__ bias, float* __restrict__ C, int N, int K)
{
    __shared__ __align__(1024) char smem[3 * 8192 + 3 * 16384];
    const int lane = threadIdx.x & 63;
    const int wave = threadIdx.x >> 6;
    const int wm0  = (wave >> 1) * 32;
    const int wn0  = (wave & 1) * 32;
    const int lr   = lane & 15;
    const int g    = lane >> 4;
    const int n0   = blockIdx.x * 64;
    const int m0   = blockIdx.y * 64;

    f32x4 acc[2][2] = {};

    auto stage = [&](int buf, int k0) {
        char* sA = smem + buf * 8192;
        char* sW = smem + 3 * 8192 + buf * 16384;
        #pragma unroll
        for (int cc = 0; cc < 2; ++cc) {
            int c  = wave * 2 + cc;                   // A: 8 chunks
            int r  = c * 8 + (lane >> 3);             // row 0..63
            int ss = (lane & 7) ^ (r & 7);            // 8 slots x 16B per row
            gl_lds16(&A[(size_t)(m0 + r) * K + k0 + ss * 8], sA + c * 1024);
        }
        #pragma unroll
        for (int cc = 0; cc < 4; ++cc) {
            int c  = wave * 4 + cc;                   // W: 16 chunks
            int r  = c * 4 + (lane >> 4);             // row 0..63
            int ss = (lane & 15) ^ (r & 15);          // 16 slots x 16B per row
            int rg = n0 + r; rg = rg < N ? rg : N - 1;
            gl_lds16(&W[(size_t)rg * K + k0 + ss * 4], sW + c * 1024);
        }
    };

    auto compute = [&](int buf) {
        char* sA = smem + buf * 8192;
        char* sW = smem + 3 * 8192 + buf * 16384;
        #pragma unroll
        for (int ks = 0; ks < 2; ++ks) {
            bf8 av[2], bv[2];
            #pragma unroll
            for (int i = 0; i < 2; ++i) {
                int ra = wm0 + i * 16 + lr;
                int sl = (ks * 4 + g) ^ (ra & 7);
                av[i] = *reinterpret_cast<const bf8*>(sA + ra * 128 + sl * 16);
            }
            #pragma unroll
            for (int j = 0; j < 2; ++j) {
                int rb = wn0 + j * 16 + lr;
                int s0 = (ks * 8 + g * 2)     ^ (rb & 15);
                int s1 = (ks * 8 + g * 2 + 1) ^ (rb & 15);
                f32x4 lo = *reinterpret_cast<const f32x4*>(sW + rb * 256 + s0 * 16);
                f32x4 hi = *reinterpret_cast<const f32x4*>(sW + rb * 256 + s1 * 16);
                bv[j] = cvt_frag(lo, hi);
            }
            #pragma unroll
            for (int i = 0; i < 2; ++i)
                #pragma unroll
                for (int j = 0; j < 2; ++j)
                    acc[i][j] = MFMA16(av[i], bv[j], acc[i][j], 0, 0, 0);
        }
    };

    const int nt = K >> 6;   // 16
    stage(0, 0); stage(1, 64);
    int bs = 2, bc = 0;
    for (int t = 0; t < nt - 2; ++t) {
        stage(bs, (t + 2) << 6);
        bs = (bs == 2) ? 0 : bs + 1;
        waitvm<12>(); BAR();
        compute(bc);
        bc = (bc == 2) ? 0 : bc + 1;
        BAR();
    }
    waitvm<6>(); BAR(); compute(bc); bc = (bc == 2) ? 0 : bc + 1; BAR();
    waitvm<0>(); BAR(); compute(bc);

    #pragma unroll
    for (int j = 0; j < 2; ++j) {
        int n = n0 + wn0 + j * 16 + lr;
        if (n >= N) continue;
        float bn_ = bias[n];
        #pragma unroll
        for (int i = 0; i < 2; ++i) {
            #pragma unroll
            for (int r = 0; r < 4; ++r) {
                int m = m0 + wm0 + i * 16 + g * 4 + r;
                C[(size_t)m * N + n] = acc[i][j][r] + bn_;
            }
        }
    }
}

// feat fp32->bf16 (all threads), hidden fp32->bf16 (first 16384), score init (first 1024)
__global__ __launch_bounds__(256) void prep_all(
    const float* __restrict__ feat, short* __restrict__ feat_bf,
    const float* __restrict__ h, short* __restrict__ h_bf,
    float* __restrict__ score, const float* __restrict__ vb)
{
    int t = blockIdx.x * 256 + threadIdx.x;    // 0..524287
    {
        float4 v0 = *reinterpret_cast<const float4*>(feat + (size_t)t * 8);
        float4 v1 = *reinterpret_cast<const float4*>(feat + (size_t)t * 8 + 4);
        uint4 q = make_uint4(pk2(v0.x, v0.y), pk2(v0.z, v0.w),
                             pk2(v1.x, v1.y), pk2(v1.z, v1.w));
        *reinterpret_cast<uint4*>(feat_bf + (size_t)t * 8) = q;
    }
    if (t < 16384) {
        float4 v0 = *reinterpret_cast<const float4*>(h + (size_t)t * 8);
        float4 v1 = *reinterpret_cast<const float4*>(h + (size_t)t * 8 + 4);
        uint4 q = make_uint4(pk2(v0.x, v0.y), pk2(v0.z, v0.w),
                             pk2(v1.x, v1.y), pk2(v1.z, v1.w));
        *reinterpret_cast<uint4*>(h_bf + (size_t)t * 8) = q;
    }
    if (t < 1024) {
        float v = vb[0];
        float4 vv = make_float4(v, v, v, v);
        *reinterpret_cast<float4*>(score + t * 8)     = vv;
        *reinterpret_cast<float4*>(score + t * 8 + 4) = vv;
    }
}

// one block per batch b: softmax over L=64, ctx = attn . features(bf16), gin_bf = [ctx, emb[x]]
__global__ __launch_bounds__(256) void softmax_ctx(
    const float* __restrict__ score, const short* __restrict__ feat_bf,
    const int* __restrict__ x, const float* __restrict__ emb,
    float* __restrict__ attn_out, short* __restrict__ gin_bf)
{
    int b = blockIdx.x;
    int t = threadIdx.x;
    __shared__ float sa[64];
    if (t < 64) {
        float v = score[b * 64 + t];
        float m = v;
        #pragma unroll
        for (int off = 32; off; off >>= 1) m = fmaxf(m, __shfl_xor(m, off));
        float e = __expf(v - m);
        float s = e;
        #pragma unroll
        for (int off = 32; off; off >>= 1) s += __shfl_xor(s, off);
        float a = e / s;
        attn_out[b * 64 + t] = a;
        sa[t] = a;
    }
    __syncthreads();
    {
        int e0 = t * 2;
        float c0 = 0.f, c1 = 0.f;
        #pragma unroll 4
        for (int l = 0; l < 64; ++l) {
            float a = sa[l];
            unsigned v = *reinterpret_cast<const unsigned*>(
                &feat_bf[((size_t)b * 64 + l) * 512 + e0]);
            c0 += a * bf2f((short)(v & 0xffff));
            c1 += a * bf2f((short)(v >> 16));
        }
        *reinterpret_cast<unsigned*>(&gin_bf[(size_t)b * 1024 + e0]) = pk2(c0, c1);
    }
    {
        int xi = x[b];
        int e0 = t * 2;
        float2 ev = *reinterpret_cast<const float2*>(&emb[(size_t)xi * 512 + e0]);
        *reinterpret_cast<unsigned*>(&gin_bf[(size_t)b * 1024 + 512 + e0]) = pk2(ev.x, ev.y);
    }
}

__global__ __launch_bounds__(256) void gru_kernel(
    const float* __restrict__ gi, const float* __restrict__ gh,
    const float* __restrict__ h, float* __restrict__ hnew,
    short* __restrict__ hnew_bf)
{
    int idx = blockIdx.x * 256 + threadIdx.x;   // 131072
    int b = idx >> 10, u = idx & 1023;
    const float* gib = gi + (size_t)b * 3072;
    const float* ghb = gh + (size_t)b * 3072;
    float ir = gib[u], iz = gib[1024 + u], in_ = gib[2048 + u];
    float hr = ghb[u], hz = ghb[1024 + u], hn = ghb[2048 + u];
    float r = 1.f / (1.f + __expf(-(ir + hr)));
    float z = 1.f / (1.f + __expf(-(iz + hz)));
    float n = fast_tanh(in_ + r * hn);
    float val = (1.f - z) * n + z * h[idx];
    hnew[idx] = val;
    hnew_bf[idx] = f2bfs(val);
}

extern "C" void kernel_launch(void* const* d_in, const int* in_sizes, int n_in,
                              void* d_out, int out_size, void* d_ws, size_t ws_size,
                              hipStream_t stream)
{
    const int*   x        = (const int*)  d_in[0];
    const float* features = (const float*)d_in[1];
    const float* hidden   = (const float*)d_in[2];
    const float* emb      = (const float*)d_in[3];
    const float* Uattn_w  = (const float*)d_in[4];
    const float* Uattn_b  = (const float*)d_in[5];
    const float* Wattn_w  = (const float*)d_in[6];
    const float* Wattn_b  = (const float*)d_in[7];
    const float* Vattn_w  = (const float*)d_in[8];
    const float* Vattn_b  = (const float*)d_in[9];
    const float* W_ih     = (const float*)d_in[10];
    const float* W_hh     = (const float*)d_in[11];
    const float* b_ih     = (const float*)d_in[12];
    const float* b_hh     = (const float*)d_in[13];
    const float* fc_w     = (const float*)d_in[14];
    const float* fc_b     = (const float*)d_in[15];
    const float* bn_gamma = (const float*)d_in[16];
    const float* bn_beta  = (const float*)d_in[17];
    const float* bn_mean  = (const float*)d_in[18];
    const float* bn_var   = (const float*)d_in[19];
    const float* fc2_w    = (const float*)d_in[20];
    const float* fc2_b    = (const float*)d_in[21];

    float* out    = (float*)d_out;
    float* logits = out;                       // 128*50257
    float* hnew   = out + 6432896;             // 131072
    float* attn   = out + 6432896 + 131072;    // 8192

    float* ws        = (float*)d_ws;
    float* Wh        = ws;                      // 131072 f
    float* scoreb    = ws + 131072;             // 8192 f
    float* gi        = ws + 139264;             // 393216 f
    float* gh        = ws + 532480;             // 393216 f
    short* hidden_bf = (short*)(ws + 925696);   // 131072 bf16
    short* gin_bf    = (short*)(ws + 991232);   // 131072 bf16
    short* hnew_bf   = (short*)(ws + 1056768);  // 131072 bf16
    short* y_bf      = (short*)(ws + 1122304);  // 131072 bf16
    short* feat_bf   = (short*)(ws + 1187840);  // 4194304 bf16

    prep_all<<<2048, 256, 0, stream>>>(features, feat_bf, hidden, hidden_bf,
                                       scoreb, Vattn_b);

    // Wh = h @ Wattn_w^T + Wattn_b
    gemm_k<0, 64, false><<<dim3(16, 2), 256, 0, stream>>>(
        hidden_bf, Wattn_w, Wattn_b, Wh, 1024, 1024, 1024,
        nullptr, nullptr, nullptr, nullptr, nullptr);

    // score[b,l] += sum_u tanh(Uf + Uattn_b + Wh) * Vattn_w
    gemm_k<2, 128, false><<<dim3(16, 64), 256, 0, stream>>>(
        feat_bf, Uattn_w, Uattn_b, nullptr, 1024, 512, 512,
        Wh, Vattn_w, nullptr, nullptr, scoreb);

    softmax_ctx<<<128, 256, 0, stream>>>(scoreb, feat_bf, x, emb, attn, gin_bf);

    // gi = gin @ W_ih^T + b_ih ; gh = h @ W_hh^T + b_hh (fused dual launch)
    gemm_dual<<<dim3(48, 2, 2), 256, 0, stream>>>(
        gin_bf, W_ih, b_ih, gi,
        hidden_bf, W_hh, b_hh, gh, 3072, 1024, 1024);

    gru_kernel<<<512, 256, 0, stream>>>(gi, gh, hidden, hnew, hnew_bf);

    // y = BN(h_new @ fc_w^T + fc_b) -> bf16
    gemm_k<1, 64, true><<<dim3(16, 2), 256, 0, stream>>>(
        hnew_bf, fc_w, fc_b, y_bf, 1024, 1024, 1024,
        bn_gamma, bn_beta, bn_mean, bn_var, nullptr);

    // logits = y @ fc2_w^T + fc2_b  (BK=64: 256B-contiguous W rows)
    gemm_fc2<<<dim3(786, 2), 256, 0, stream>>>(y_bf, fc2_w, fc2_b, logits, 50257, 1024);
}

// Round 19
// 141.173 us; speedup vs baseline: 1.1217x; 1.1217x over previous
//
#include <hip/hip_runtime.h>

typedef short bf8 __attribute__((ext_vector_type(8)));
typedef float f32x4 __attribute__((ext_vector_type(4)));

__device__ inline short f2bfs(float f) {
    unsigned u = __builtin_bit_cast(unsigned, f);
    u += 0x7FFFu + ((u >> 16) & 1u);
    return (short)(u >> 16);
}

__device__ inline unsigned pk2(float x, float y) {
    return (unsigned)(unsigned short)f2bfs(x) |
           ((unsigned)(unsigned short)f2bfs(y) << 16);
}

__device__ inline float bf2f(short s) {
    unsigned u = ((unsigned)(unsigned short)s) << 16;
    return __builtin_bit_cast(float, u);
}

__device__ inline bf8 cvt_frag(f32x4 lo, f32x4 hi) {
    union { bf8 v; unsigned u[4]; } r;
    r.u[0] = pk2(lo[0], lo[1]);
    r.u[1] = pk2(lo[2], lo[3]);
    r.u[2] = pk2(hi[0], hi[1]);
    r.u[3] = pk2(hi[2], hi[3]);
    return r.v;
}

__device__ inline float fast_tanh(float x) {
    x = fminf(fmaxf(x, -15.f), 15.f);
    float e = __expf(2.f * x);
    return (e - 1.f) / (e + 1.f);
}

__device__ inline void gl_lds16(const void* g, void* l) {
    __builtin_amdgcn_global_load_lds(
        (const __attribute__((address_space(1))) unsigned int*)g,
        (__attribute__((address_space(3))) unsigned int*)l,
        16, 0, 0);
}

#define BAR() asm volatile("s_barrier" ::: "memory")

template<int N> __device__ __forceinline__ void waitvm() {
    if constexpr (N == 8)      asm volatile("s_waitcnt vmcnt(8)"  ::: "memory");
    else if constexpr (N == 6) asm volatile("s_waitcnt vmcnt(6)"  ::: "memory");
    else if constexpr (N == 4) asm volatile("s_waitcnt vmcnt(4)"  ::: "memory");
    else if constexpr (N == 3) asm volatile("s_waitcnt vmcnt(3)"  ::: "memory");
    else                       asm volatile("s_waitcnt vmcnt(0)"  ::: "memory");
}

#define MFMA16 __builtin_amdgcn_mfma_f32_16x16x32_bf16

// C[M,N] = A[M,K] @ W[N,K]^T (+bias, +epilogue). BN=64, BK=32, 4 waves (2x2).
// A bf16 (pitch lda), W fp32 (cvt to bf16 on LDS read).
// 3-buffer LDS pipeline, depth-2 prefetch, counted vmcnt + raw s_barrier.
// EPI 0: C = acc + bias        EPI 1: BN-inference (q0..q3 = gamma,beta,mean,var)
// EPI 2: atomicAdd(score[m], sum_n fast_tanh(acc+bias[n]+q0[(m>>6)*N+n])*q1[n])
template<int EPI, int BM_, bool OBF>
__device__ __forceinline__ void gemm_body(
    char* smem,
    const short* __restrict__ A, const float* __restrict__ W,
    const float* __restrict__ bias, void* __restrict__ Cv,
    int N, int K, int lda, int n0, int m0,
    const float* __restrict__ q0, const float* __restrict__ q1,
    const float* __restrict__ q2, const float* __restrict__ q3,
    float* __restrict__ score)
{
    constexpr int FM  = BM_ / 32;      // m-frags per wave
    constexpr int ATS = BM_ * 64;      // A tile bytes (BM_ x 32 bf16)
    constexpr int LPT = (BM_ == 128) ? 4 : 3;   // loads/tile/wave

    const int lane = threadIdx.x & 63;
    const int wave = threadIdx.x >> 6;
    const int wm0  = (wave >> 1) * (BM_ / 2);
    const int wn0  = (wave & 1) * 32;
    const int lr   = lane & 15;
    const int g    = lane >> 4;

    f32x4 acc[FM][2] = {};

    auto stage = [&](int buf, int k0) {
        char* sA = smem + buf * ATS;
        char* sW = smem + 3 * ATS + buf * 8192;
        #pragma unroll
        for (int cc = 0; cc < BM_ / 64; ++cc) {
            int c  = wave * (BM_ / 64) + cc;
            int r  = c * 16 + (lane >> 2);
            int ss = (lane & 3) ^ ((r >> 1) & 3);
            gl_lds16(&A[(size_t)(m0 + r) * lda + k0 + ss * 8], sA + c * 1024);
        }
        #pragma unroll
        for (int cc = 0; cc < 2; ++cc) {
            int c  = wave * 2 + cc;
            int r  = c * 8 + (lane >> 3);
            int ss = (lane & 7) ^ (r & 7);
            int rg = n0 + r; rg = rg < N ? rg : N - 1;   // clamp tail
            gl_lds16(&W[(size_t)rg * K + k0 + ss * 4], sW + c * 1024);
        }
    };

    auto compute = [&](int buf) {
        char* sA = smem + buf * ATS;
        char* sW = smem + 3 * ATS + buf * 8192;
        bf8 av[FM], bv[2];
        #pragma unroll
        for (int i = 0; i < FM; ++i) {
            int ra = wm0 + i * 16 + lr;
            int sl = g ^ ((ra >> 1) & 3);
            av[i] = *reinterpret_cast<const bf8*>(sA + ra * 64 + sl * 16);
        }
        #pragma unroll
        for (int j = 0; j < 2; ++j) {
            int rb = wn0 + j * 16 + lr;
            int l0 = (2 * g)     ^ (rb & 7);
            int l1 = (2 * g + 1) ^ (rb & 7);
            f32x4 lo = *reinterpret_cast<const f32x4*>(sW + rb * 128 + l0 * 16);
            f32x4 hi = *reinterpret_cast<const f32x4*>(sW + rb * 128 + l1 * 16);
            bv[j] = cvt_frag(lo, hi);
        }
        #pragma unroll
        for (int i = 0; i < FM; ++i)
            #pragma unroll
            for (int j = 0; j < 2; ++j)
                acc[i][j] = MFMA16(av[i], bv[j], acc[i][j], 0, 0, 0);
    };

    const int nt = K >> 5;
    stage(0, 0); stage(1, 32);
    int bs = 2, bc = 0;
    for (int t = 0; t < nt - 2; ++t) {
        stage(bs, (t + 2) << 5);
        bs = (bs == 2) ? 0 : bs + 1;
        waitvm<2 * LPT>(); BAR();
        compute(bc);
        bc = (bc == 2) ? 0 : bc + 1;
        BAR();
    }
    waitvm<1 * LPT>(); BAR(); compute(bc); bc = (bc == 2) ? 0 : bc + 1; BAR();
    waitvm<0>();       BAR(); compute(bc);

    if constexpr (EPI == 2) {
        #pragma unroll
        for (int i = 0; i < FM; ++i) {
            #pragma unroll
            for (int r = 0; r < 4; ++r) {
                int m = m0 + wm0 + i * 16 + g * 4 + r;
                int bidx = m >> 6;
                float s = 0.f;
                #pragma unroll
                for (int j = 0; j < 2; ++j) {
                    int n = n0 + wn0 + j * 16 + lr;
                    s += fast_tanh(acc[i][j][r] + bias[n] + q0[(size_t)bidx * N + n]) * q1[n];
                }
                #pragma unroll
                for (int off = 1; off < 16; off <<= 1)
                    s += __shfl_xor(s, off);
                if (lr == 0) atomicAdd(&score[m], s);
            }
        }
    } else {
        #pragma unroll
        for (int j = 0; j < 2; ++j) {
            int n = n0 + wn0 + j * 16 + lr;
            if (n >= N) continue;
            float bn_ = bias[n];
            float sc = 1.f, sh = 0.f;
            if constexpr (EPI == 1) {
                sc = q0[n] * rsqrtf(q3[n] + 1e-3f);
                sh = q1[n] - q2[n] * sc;
            }
            #pragma unroll
            for (int i = 0; i < FM; ++i) {
                #pragma unroll
                for (int r = 0; r < 4; ++r) {
                    int m = m0 + wm0 + i * 16 + g * 4 + r;
                    float v = acc[i][j][r] + bn_;
                    if constexpr (EPI == 1) v = v * sc + sh;
                    if constexpr (OBF) ((short*)Cv)[(size_t)m * N + n] = f2bfs(v);
                    else               ((float*)Cv)[(size_t)m * N + n] = v;
                }
            }
        }
    }
}

template<int EPI, int BM_, bool OBF>
__global__ __launch_bounds__(256) void gemm_k(
    const short* __restrict__ A, const float* __restrict__ W,
    const float* __restrict__ bias, void* __restrict__ Cv,
    int N, int K, int lda,
    const float* __restrict__ q0, const float* __restrict__ q1,
    const float* __restrict__ q2, const float* __restrict__ q3,
    float* __restrict__ score)
{
    __shared__ __align__(1024) char smem[3 * BM_ * 64 + 3 * 8192];
    gemm_body<EPI, BM_, OBF>(smem, A, W, bias, Cv, N, K, lda,
                             blockIdx.x * 64, blockIdx.y * BM_,
                             q0, q1, q2, q3, score);
}

// z=0: C0 = A0@W0^T+b0 ; z=1: C1 = A1@W1^T+b1  (BM=64)
__global__ __launch_bounds__(256) void gemm_dual(
    const short* __restrict__ A0, const float* __restrict__ W0,
    const float* __restrict__ b0, float* __restrict__ C0,
    const short* __restrict__ A1, const float* __restrict__ W1,
    const float* __restrict__ b1, float* __restrict__ C1,
    int N, int K, int lda)
{
    __shared__ __align__(1024) char smem[3 * 64 * 64 + 3 * 8192];
    if (blockIdx.z == 0)
        gemm_body<0, 64, false>(smem, A0, W0, b0, C0, N, K, lda,
                                blockIdx.x * 64, blockIdx.y * 64,
                                nullptr, nullptr, nullptr, nullptr, nullptr);
    else
        gemm_body<0, 64, false>(smem, A1, W1, b1, C1, N, K, lda,
                                blockIdx.x * 64, blockIdx.y * 64,
                                nullptr, nullptr, nullptr, nullptr, nullptr);
}

// fc2 (BK=64, single M-block): logits = y_bf(128xK) @ fc2_w^T + fc2_b.
// BM=128, BN=64, BK=64, 16 iters; W rows stream as 256B contiguous bursts
// and fc2_w is read ONCE (R18 read it twice). 2-buffer depth-1 counted-vmcnt
// (LPT=8/wave: A 4 chunks + W 4 chunks); steady wait vmcnt(8), tail 0.
// 64KB LDS -> 2 blocks/CU. A LDS: 128x64 bf16, slot^(row&7) over 8 slots;
// W LDS: 64x64 fp32, slot^(row&15) over 16 slots (verified in R18).
__global__ __launch_bounds__(256) void gemm_fc2(
    const short* __restrict__ A, const float* __restrict__ W,
    const float* __restrict__ bias, float* __restrict__ C, int N, int K)
{
    __shared__ __align__(1024) char smem[2 * 16384 + 2 * 16384];
    const int lane = threadIdx.x & 63;
    const int wave = threadIdx.x >> 6;
    const int wm0  = (wave >> 1) * 64;
    const int wn0  = (wave & 1) * 32;
    const int lr   = lane & 15;
    const int g    = lane >> 4;
    const int n0   = blockIdx.x * 64;

    f32x4 acc[4][2] = {};

    auto stage = [&](int buf, int k0) {
        char* sA = smem + buf * 16384;
        char* sW = smem + 32768 + buf * 16384;
        #pragma unroll
        for (int cc = 0; cc < 4; ++cc) {
            int c  = wave * 4 + cc;                   // A: 16 chunks, 8 rows each
            int r  = c * 8 + (lane >> 3);
            int ss = (lane & 7) ^ (r & 7);
            gl_lds16(&A[(size_t)r * K + k0 + ss * 8], sA + c * 1024);
        }
        #pragma unroll
        for (int cc = 0; cc < 4; ++cc) {
            int c  = wave * 4 + cc;                   // W: 16 chunks, 4 rows each
            int r  = c * 4 + (lane >> 4);
            int ss = (lane & 15) ^ (r & 15);
            int rg = n0 + r; rg = rg < N ? rg : N - 1;
            gl_lds16(&W[(size_t)rg * K + k0 + ss * 4], sW + c * 1024);
        }
    };

    auto compute = [&](int buf) {
        char* sA = smem + buf * 16384;
        char* sW = smem + 32768 + buf * 16384;
        #pragma unroll
        for (int ks = 0; ks < 2; ++ks) {
            bf8 av[4], bv[2];
            #pragma unroll
            for (int i = 0; i < 4; ++i) {
                int ra = wm0 + i * 16 + lr;
                int sl = (ks * 4 + g) ^ (ra & 7);
                av[i] = *reinterpret_cast<const bf8*>(sA + ra * 128 + sl * 16);
            }
            #pragma unroll
            for (int j = 0; j < 2; ++j) {
                int rb = wn0 + j * 16 + lr;
                int s0 = (ks * 8 + g * 2)     ^ (rb & 15);
                int s1 = (ks * 8 + g * 2 + 1) ^ (rb & 15);
                f32x4 lo = *reinterpret_cast<const f32x4*>(sW + rb * 256 + s0 * 16);
                f32x4 hi = *reinterpret_cast<const f32x4*>(sW + rb * 256 + s1 * 16);
                bv[j] = cvt_frag(lo, hi);
            }
            #pragma unroll
            for (int i = 0; i < 4; ++i)
                #pragma unroll
                for (int j = 0; j < 2; ++j)
                    acc[i][j] = MFMA16(av[i], bv[j], acc[i][j], 0, 0, 0);
        }
    };

    const int nt = K >> 6;   // 16
    stage(0, 0);
    for (int t = 0; t < nt; ++t) {
        if (t + 1 < nt) { stage((t + 1) & 1, (t + 1) << 6); waitvm<8>(); }
        else            { waitvm<0>(); }
        BAR();
        compute(t & 1);
        BAR();
    }

    #pragma unroll
    for (int j = 0; j < 2; ++j) {
        int n = n0 + wn0 + j * 16 + lr;
        if (n >= N) continue;
        float bn_ = bias[n];
        #pragma unroll
        for (int i = 0; i < 4; ++i) {
            #pragma unroll
            for (int r = 0; r < 4; ++r) {
                int m = wm0 + i * 16 + g * 4 + r;
                C[(size_t)m * N + n] = acc[i][j][r] + bn_;
            }
        }
    }
}

// feat fp32->bf16 (all threads), hidden fp32->bf16 (first 16384), score init (first 1024)
__global__ __launch_bounds__(256) void prep_all(
    const float* __restrict__ feat, short* __restrict__ feat_bf,
    const float* __restrict__ h, short* __restrict__ h_bf,
    float* __restrict__ score, const float* __restrict__ vb)
{
    int t = blockIdx.x * 256 + threadIdx.x;    // 0..524287
    {
        float4 v0 = *reinterpret_cast<const float4*>(feat + (size_t)t * 8);
        float4 v1 = *reinterpret_cast<const float4*>(feat + (size_t)t * 8 + 4);
        uint4 q = make_uint4(pk2(v0.x, v0.y), pk2(v0.z, v0.w),
                             pk2(v1.x, v1.y), pk2(v1.z, v1.w));
        *reinterpret_cast<uint4*>(feat_bf + (size_t)t * 8) = q;
    }
    if (t < 16384) {
        float4 v0 = *reinterpret_cast<const float4*>(h + (size_t)t * 8);
        float4 v1 = *reinterpret_cast<const float4*>(h + (size_t)t * 8 + 4);
        uint4 q = make_uint4(pk2(v0.x, v0.y), pk2(v0.z, v0.w),
                             pk2(v1.x, v1.y), pk2(v1.z, v1.w));
        *reinterpret_cast<uint4*>(h_bf + (size_t)t * 8) = q;
    }
    if (t < 1024) {
        float v = vb[0];
        float4 vv = make_float4(v, v, v, v);
        *reinterpret_cast<float4*>(score + t * 8)     = vv;
        *reinterpret_cast<float4*>(score + t * 8 + 4) = vv;
    }
}

// one block per batch b: softmax over L=64, ctx = attn . features(bf16), gin_bf = [ctx, emb[x]]
__global__ __launch_bounds__(256) void softmax_ctx(
    const float* __restrict__ score, const short* __restrict__ feat_bf,
    const int* __restrict__ x, const float* __restrict__ emb,
    float* __restrict__ attn_out, short* __restrict__ gin_bf)
{
    int b = blockIdx.x;
    int t = threadIdx.x;
    __shared__ float sa[64];
    if (t < 64) {
        float v = score[b * 64 + t];
        float m = v;
        #pragma unroll
        for (int off = 32; off; off >>= 1) m = fmaxf(m, __shfl_xor(m, off));
        float e = __expf(v - m);
        float s = e;
        #pragma unroll
        for (int off = 32; off; off >>= 1) s += __shfl_xor(s, off);
        float a = e / s;
        attn_out[b * 64 + t] = a;
        sa[t] = a;
    }
    __syncthreads();
    {
        int e0 = t * 2;
        float c0 = 0.f, c1 = 0.f;
        #pragma unroll 4
        for (int l = 0; l < 64; ++l) {
            float a = sa[l];
            unsigned v = *reinterpret_cast<const unsigned*>(
                &feat_bf[((size_t)b * 64 + l) * 512 + e0]);
            c0 += a * bf2f((short)(v & 0xffff));
            c1 += a * bf2f((short)(v >> 16));
        }
        *reinterpret_cast<unsigned*>(&gin_bf[(size_t)b * 1024 + e0]) = pk2(c0, c1);
    }
    {
        int xi = x[b];
        int e0 = t * 2;
        float2 ev = *reinterpret_cast<const float2*>(&emb[(size_t)xi * 512 + e0]);
        *reinterpret_cast<unsigned*>(&gin_bf[(size_t)b * 1024 + 512 + e0]) = pk2(ev.x, ev.y);
    }
}

__global__ __launch_bounds__(256) void gru_kernel(
    const float* __restrict__ gi, const float* __restrict__ gh,
    const float* __restrict__ h, float* __restrict__ hnew,
    short* __restrict__ hnew_bf)
{
    int idx = blockIdx.x * 256 + threadIdx.x;   // 131072
    int b = idx >> 10, u = idx & 1023;
    const float* gib = gi + (size_t)b * 3072;
    const float* ghb = gh + (size_t)b * 3072;
    float ir = gib[u], iz = gib[1024 + u], in_ = gib[2048 + u];
    float hr = ghb[u], hz = ghb[1024 + u], hn = ghb[2048 + u];
    float r = 1.f / (1.f + __expf(-(ir + hr)));
    float z = 1.f / (1.f + __expf(-(iz + hz)));
    float n = fast_tanh(in_ + r * hn);
    float val = (1.f - z) * n + z * h[idx];
    hnew[idx] = val;
    hnew_bf[idx] = f2bfs(val);
}

extern "C" void kernel_launch(void* const* d_in, const int* in_sizes, int n_in,
                              void* d_out, int out_size, void* d_ws, size_t ws_size,
                              hipStream_t stream)
{
    const int*   x        = (const int*)  d_in[0];
    const float* features = (const float*)d_in[1];
    const float* hidden   = (const float*)d_in[2];
    const float* emb      = (const float*)d_in[3];
    const float* Uattn_w  = (const float*)d_in[4];
    const float* Uattn_b  = (const float*)d_in[5];
    const float* Wattn_w  = (const float*)d_in[6];
    const float* Wattn_b  = (const float*)d_in[7];
    const float* Vattn_w  = (const float*)d_in[8];
    const float* Vattn_b  = (const float*)d_in[9];
    const float* W_ih     = (const float*)d_in[10];
    const float* W_hh     = (const float*)d_in[11];
    const float* b_ih     = (const float*)d_in[12];
    const float* b_hh     = (const float*)d_in[13];
    const float* fc_w     = (const float*)d_in[14];
    const float* fc_b     = (const float*)d_in[15];
    const float* bn_gamma = (const float*)d_in[16];
    const float* bn_beta  = (const float*)d_in[17];
    const float* bn_mean  = (const float*)d_in[18];
    const float* bn_var   = (const float*)d_in[19];
    const float* fc2_w    = (const float*)d_in[20];
    const float* fc2_b    = (const float*)d_in[21];

    float* out    = (float*)d_out;
    float* logits = out;                       // 128*50257
    float* hnew   = out + 6432896;             // 131072
    float* attn   = out + 6432896 + 131072;    // 8192

    float* ws        = (float*)d_ws;
    float* Wh        = ws;                      // 131072 f
    float* scoreb    = ws + 131072;             // 8192 f
    float* gi        = ws + 139264;             // 393216 f
    float* gh        = ws + 532480;             // 393216 f
    short* hidden_bf = (short*)(ws + 925696);   // 131072 bf16
    short* gin_bf    = (short*)(ws + 991232);   // 131072 bf16
    short* hnew_bf   = (short*)(ws + 1056768);  // 131072 bf16
    short* y_bf      = (short*)(ws + 1122304);  // 131072 bf16
    short* feat_bf   = (short*)(ws + 1187840);  // 4194304 bf16

    prep_all<<<2048, 256, 0, stream>>>(features, feat_bf, hidden, hidden_bf,
                                       scoreb, Vattn_b);

    // Wh = h @ Wattn_w^T + Wattn_b
    gemm_k<0, 64, false><<<dim3(16, 2), 256, 0, stream>>>(
        hidden_bf, Wattn_w, Wattn_b, Wh, 1024, 1024, 1024,
        nullptr, nullptr, nullptr, nullptr, nullptr);

    // score[b,l] += sum_u tanh(Uf + Uattn_b + Wh) * Vattn_w
    gemm_k<2, 128, false><<<dim3(16, 64), 256, 0, stream>>>(
        feat_bf, Uattn_w, Uattn_b, nullptr, 1024, 512, 512,
        Wh, Vattn_w, nullptr, nullptr, scoreb);

    softmax_ctx<<<128, 256, 0, stream>>>(scoreb, feat_bf, x, emb, attn, gin_bf);

    // gi = gin @ W_ih^T + b_ih ; gh = h @ W_hh^T + b_hh (fused dual launch)
    gemm_dual<<<dim3(48, 2, 2), 256, 0, stream>>>(
        gin_bf, W_ih, b_ih, gi,
        hidden_bf, W_hh, b_hh, gh, 3072, 1024, 1024);

    gru_kernel<<<512, 256, 0, stream>>>(gi, gh, hidden, hnew, hnew_bf);

    // y = BN(h_new @ fc_w^T + fc_b) -> bf16
    gemm_k<1, 64, true><<<dim3(16, 2), 256, 0, stream>>>(
        hnew_bf, fc_w, fc_b, y_bf, 1024, 1024, 1024,
        bn_gamma, bn_beta, bn_mean, bn_var, nullptr);

    // logits = y @ fc2_w^T + fc2_b  (BK=64, W read once, 786 blocks)
    gemm_fc2<<<786, 256, 0, stream>>>(y_bf, fc2_w, fc2_b, logits, 50257, 1024);
}